// Round 10
// baseline (7719.314 us; speedup 1.0000x reference)
//
#include <hip/hip_runtime.h>
#include <hip/hip_bf16.h>
#include <stdint.h>

#define T_STEPS 512
#define BATCH   256
#define HID     256

#define NRC    16      // recurrence WGs: 16 batch rows each, ALL gates, Wh in VGPRs
#define NWWG   240     // xgemm producer WGs
#define NWG    256
#define RING   4       // ring slots
#define CHUNK  8       // time steps per chunk
#define NCHUNK 64
#define TPC    32      // tiles per chunk: (8*256/256) * (1024/256)
#define SLOT_F (CHUNK*256*1024)   // floats per ring slot (8 MB)

using short8 = __attribute__((ext_vector_type(8))) short;
using us4    = __attribute__((ext_vector_type(4))) unsigned short;
using f32x4  = __attribute__((ext_vector_type(4))) float;

#define VMCNT0() asm volatile("s_waitcnt vmcnt(0)" ::: "memory")

__device__ inline unsigned short f2bf(float f) {
  unsigned u = __float_as_uint(f);
  unsigned r = (u + 0x7fffu + ((u >> 16) & 1u)) >> 16;
  return (unsigned short)r;
}
__device__ inline float sigm(float x)   { return __builtin_amdgcn_rcpf(1.0f + __expf(-x)); }
__device__ inline float tanh_f(float x) { return 2.0f * __builtin_amdgcn_rcpf(1.0f + __expf(-2.0f * x)) - 1.0f; }

__device__ inline int ld_rlx(const int* p) {
  return __hip_atomic_load(p, __ATOMIC_RELAXED, __HIP_MEMORY_SCOPE_AGENT);
}
__device__ inline void add_rlx(int* p, int v) {
  __hip_atomic_fetch_add(p, v, __ATOMIC_RELAXED, __HIP_MEMORY_SCOPE_AGENT);
}
__device__ inline float ldg_coh(const float* p) {
  return __hip_atomic_load(p, __ATOMIC_RELAXED, __HIP_MEMORY_SCOPE_AGENT);
}
__device__ inline void stg_coh(float* p, float v) {
  __hip_atomic_store(p, v, __ATOMIC_RELAXED, __HIP_MEMORY_SCOPE_AGENT);
}

// h LDS swizzle (proven r5-r9): XOR bits 4..5 with bits 8..9; preserves 8/16B runs
__device__ inline int hswz(int byte) { return byte ^ (((byte >> 8) & 3) << 4); }

struct RecSm {
  unsigned short hL[4096];      // 8 KB frag-linear h (16 batch x 256 k, bf16)
  float z[16][520];             // 33.3 KB half-z staging (512 cols + pad)
  int rdy;
};
struct GemSm { unsigned short aL[8192]; unsigned short bL[8192]; };  // 32 KB

// ---------------- prep: pack weights + zero flags ----------------
// Wfull : [1024 cols][768 k] bf16 (k 0..511 = x part, 512..767 = h part)
__global__ __launch_bounds__(256) void prep_kernel(
    const float* __restrict__ Wf, const float* __restrict__ Wi,
    const float* __restrict__ Wg, const float* __restrict__ Wo,
    const float* __restrict__ bf_, const float* __restrict__ bi_,
    const float* __restrict__ bg_, const float* __restrict__ bo_,
    const float* __restrict__ thf, const float* __restrict__ thi,
    const float* __restrict__ thg, const float* __restrict__ tho,
    unsigned short* __restrict__ Wfull, float* __restrict__ cvec,
    int* __restrict__ flags)
{
  int j = blockIdx.x;            // 0..1023 output col
  int g = j >> 8, col = j & 255;
  const float* W  = (g==0)?Wf:(g==1)?Wi:(g==2)?Wg:Wo;
  const float* bb = (g==0)?bf_:(g==1)?bi_:(g==2)?bg_:bo_;
  const float* th = (g==0)?thf:(g==1)?thi:(g==2)?thg:tho;
  const float* wrow = W + (size_t)col * 768;
  for (int k = threadIdx.x; k < 768; k += blockDim.x)
    Wfull[(size_t)j * 768 + k] = f2bf(wrow[k]);
  if (threadIdx.x == 0) cvec[j] = bb[col] + th[col];
  if (j == 0) for (int i = threadIdx.x; i < 512; i += 256) flags[i] = 0;
}

// ---------------- persistent kernel (1024 threads, 16 waves) ----------------
// blocks 0..15   : recurrence, rows bid*16..+15, all gates, Wh in registers
// blocks 16..255 : xgemm producers filling the Zx ring (256x256 tiles)
__global__ __launch_bounds__(1024, 4) void persist_kernel(
    const float* __restrict__ X,
    const unsigned short* __restrict__ Wfull,
    const float* __restrict__ cvec,
    float* __restrict__ ring,
    int* __restrict__ done,       // [64]
    int* __restrict__ consumed,   // [1]
    float* __restrict__ out)
{
  __shared__ union { RecSm rec; GemSm gem; } sm;

  int bid = blockIdx.x, tid = threadIdx.x;
  int lane = tid & 63, wv = tid >> 6;       // 16 waves
  int l15 = lane & 15, lk = lane >> 4;

  if (bid < NRC) {
    // ============ recurrence: Wh fully register-resident in 16 waves ============
    int bg = bid;
    int cs = wv * 64;                        // this wave's 64 gate-cols

    for (int i = tid; i < 4096; i += 1024) sm.rec.hL[i] = 0;
    if (tid == 0) sm.rec.rdy = 0;

    // one-time Wh preload: 4 col-tiles x 8 k-frags = 128 VGPRs/lane
    short8 af[4][8];
#pragma unroll
    for (int ct = 0; ct < 4; ++ct)
#pragma unroll
      for (int kk = 0; kk < 8; ++kk)
        af[ct][kk] = *(const short8*)(Wfull +
            (size_t)(cs + ct*16 + l15)*768 + 512 + kk*32 + lk*8);

    f32x4 cr = {0.f, 0.f, 0.f, 0.f};         // c-state: row=wv, cols 4*lane..+3
    __syncthreads();

    for (int t = 0; t < T_STEPS; ++t) {
      int cIdx = t >> 3;

      // ---- chunk gate (uniform LDS-speculated branch) ----
      if ((t & 7) == 0) {
        if (sm.rec.rdy < TPC) {
          if (tid == 0) { while (ld_rlx(&done[cIdx]) < TPC) __builtin_amdgcn_s_sleep(1); }
          __syncthreads();
        }
      }

      // ---- zx issue (wave wv = batch row wv); latency hides under MFMA ----
      const float* zp = ring + (size_t)(cIdx & (RING-1))*SLOT_F
                      + ((size_t)(t & 7)*256 + bg*16 + wv)*1024 + 4*lane;
      float zx[4][4];
#pragma unroll
      for (int g = 0; g < 4; ++g)
#pragma unroll
        for (int j = 0; j < 4; ++j) zx[g][j] = ldg_coh(zp + g*256 + j);

      // ---- MFMA: z = Wh(cols, regs) x h(16 batch, LDS) ----
      short8 hb[8];
#pragma unroll
      for (int kk = 0; kk < 8; ++kk)
        hb[kk] = *(const short8*)((const char*)sm.rec.hL + hswz(kk*1024 + lane*16));
      f32x4 acc[4];
#pragma unroll
      for (int ct = 0; ct < 4; ++ct) acc[ct] = (f32x4){0.f,0.f,0.f,0.f};
#pragma unroll
      for (int kk = 0; kk < 8; ++kk)
#pragma unroll
        for (int ct = 0; ct < 4; ++ct)
          acc[ct] = __builtin_amdgcn_mfma_f32_16x16x32_bf16(af[ct][kk], hb[kk], acc[ct], 0, 0, 0);

      // ---- half-round A: waves 0..7 (gates f,i / cols 0..511) publish z ----
      if (wv < 8) {
#pragma unroll
        for (int ct = 0; ct < 4; ++ct)
          *(f32x4*)&sm.rec.z[l15][cs + ct*16 + lk*4] = acc[ct];
      }
      __syncthreads();

      float actA[2][4];                      // f, i
#pragma unroll
      for (int gg = 0; gg < 2; ++gg) {
        float vvv[4];
        f32x4 zz = *(const f32x4*)&sm.rec.z[wv][gg*256 + 4*lane];
#pragma unroll
        for (int j = 0; j < 4; ++j) vvv[j] = __cosf(zz[j] + zx[gg][j]);
        float S = vvv[0]*vvv[1]*vvv[2]*vvv[3];
#pragma unroll
        for (int off = 1; off < 64; off <<= 1) {
          float u = __shfl_up(S, (unsigned)off, 64);
          if (lane >= off) S *= u;
        }
        float e = __shfl_up(S, 1u, 64);
        float E = (lane == 0) ? 1.0f : e;
        float o0 = E*vvv[0], o1 = o0*vvv[1], o2 = o1*vvv[2], o3 = o2*vvv[3];
        actA[gg][0]=sigm(o0); actA[gg][1]=sigm(o1); actA[gg][2]=sigm(o2); actA[gg][3]=sigm(o3);
      }
      __syncthreads();

      // ---- half-round B: waves 8..15 (gates g,o / cols 512..1023) publish z ----
      if (wv >= 8) {
#pragma unroll
        for (int ct = 0; ct < 4; ++ct)
          *(f32x4*)&sm.rec.z[l15][cs - 512 + ct*16 + lk*4] = acc[ct];
      }
      __syncthreads();

      float actB[2][4];                      // g, o
#pragma unroll
      for (int gg = 0; gg < 2; ++gg) {
        float vvv[4];
        f32x4 zz = *(const f32x4*)&sm.rec.z[wv][gg*256 + 4*lane];
#pragma unroll
        for (int j = 0; j < 4; ++j) vvv[j] = __cosf(zz[j] + zx[2+gg][j]);
        float S = vvv[0]*vvv[1]*vvv[2]*vvv[3];
#pragma unroll
        for (int off = 1; off < 64; off <<= 1) {
          float u = __shfl_up(S, (unsigned)off, 64);
          if (lane >= off) S *= u;
        }
        float e = __shfl_up(S, 1u, 64);
        float E = (lane == 0) ? 1.0f : e;
        float o0 = E*vvv[0], o1 = o0*vvv[1], o2 = o1*vvv[2], o3 = o2*vvv[3];
        if (gg == 0) { actB[0][0]=tanh_f(o0); actB[0][1]=tanh_f(o1);
                       actB[0][2]=tanh_f(o2); actB[0][3]=tanh_f(o3); }
        else         { actB[1][0]=sigm(o0);   actB[1][1]=sigm(o1);
                       actB[1][2]=sigm(o2);   actB[1][3]=sigm(o3); }
      }

      // ---- LSTM update; h -> LDS + out ----
      float hv[4];
#pragma unroll
      for (int j = 0; j < 4; ++j) {
        float cn = actA[0][j]*cr[j] + actA[1][j]*actB[0][j];
        cr[j] = cn;
        hv[j] = actB[1][j]*tanh_f(cn);
      }
      {
        int k = 4*lane;
        int byte = (k >> 5)*1024 + ((k >> 3) & 3)*256 + wv*16 + (k & 7)*2;
        us4 hp = { f2bf(hv[0]), f2bf(hv[1]), f2bf(hv[2]), f2bf(hv[3]) };
        *(us4*)((char*)sm.rec.hL + hswz(byte)) = hp;
        int brow = bg*16 + wv;
        f32x4 ho = { hv[0], hv[1], hv[2], hv[3] };
        *(f32x4*)&out[(size_t)t*(BATCH*HID) + (size_t)brow*256 + k] = ho;
        if (t == T_STEPS-1) {
          *(f32x4*)&out[(size_t)T_STEPS*(BATCH*HID) + (size_t)brow*256 + k] = ho;
          *(f32x4*)&out[(size_t)T_STEPS*(BATCH*HID) + BATCH*HID + (size_t)brow*256 + k] = cr;
        }
      }

      // ---- speculation (only 2 steps before boundary) + consumed ----
      if ((t & 7) == 6 && tid == 0) sm.rec.rdy = ld_rlx(&done[cIdx + 1]);
      if ((t & 7) == 7 && tid == 0) add_rlx(consumed, 1);
      __syncthreads();   // hL(t) complete; z reads done
    }
  } else {
    // ============ xgemm producers: 256x256 tiles, 16 waves ============
    int w0 = bid - NRC;
    int wr = wv >> 2, wc = wv & 3;          // 4 x 4 wave grid, 64x64 per wave
    int rA = tid >> 2, kA = (tid & 3) * 8;  // staging: 256 rows x 32 k
    int slotA = (rA >> 4)*1024 + ((tid & 3)*16 + (rA & 15))*16;

    for (int gt = w0; gt < NCHUNK * TPC; gt += NWWG) {
      int c  = gt >> 5;
      int tl = gt & 31;
      int tm = tl >> 2, tn = tl & 3;

      int need = NRC * (c - RING + 1);
      if (need > 0) {
        if (tid == 0) { while (ld_rlx(consumed) < need) __builtin_amdgcn_s_sleep(8); }
        __syncthreads();
      }

      const float* Xb = X + ((size_t)c*(CHUNK*256) + (size_t)tm*256) * 512;
      float* slotp = ring + (size_t)(c & (RING-1)) * SLOT_F;

      f32x4 acc[4][4];
#pragma unroll
      for (int mi = 0; mi < 4; ++mi)
#pragma unroll
        for (int ni = 0; ni < 4; ++ni) acc[mi][ni] = (f32x4){0.f,0.f,0.f,0.f};

      for (int kb = 0; kb < 512; kb += 32) {
        const float* ap = Xb + (size_t)rA*512 + kb + kA;
        f32x4 v0 = *(const f32x4*)ap;
        f32x4 v1 = *(const f32x4*)(ap + 4);
        unsigned short t8[8];
        t8[0]=f2bf(v0[0]); t8[1]=f2bf(v0[1]); t8[2]=f2bf(v0[2]); t8[3]=f2bf(v0[3]);
        t8[4]=f2bf(v1[0]); t8[5]=f2bf(v1[1]); t8[6]=f2bf(v1[2]); t8[7]=f2bf(v1[3]);
        *(short8*)((char*)sm.gem.aL + slotA) = *(short8*)t8;
        const unsigned short* bp = Wfull + (size_t)(tn*256 + rA)*768 + kb + kA;
        *(short8*)((char*)sm.gem.bL + slotA) = *(const short8*)bp;
        __syncthreads();

        short8 afr[4], bfr[4];
#pragma unroll
        for (int mi = 0; mi < 4; ++mi)
          afr[mi] = *(const short8*)((const char*)sm.gem.aL + (wr*4 + mi)*1024 + lane*16);
#pragma unroll
        for (int ni = 0; ni < 4; ++ni)
          bfr[ni] = *(const short8*)((const char*)sm.gem.bL + (wc*4 + ni)*1024 + lane*16);
#pragma unroll
        for (int mi = 0; mi < 4; ++mi)
#pragma unroll
          for (int ni = 0; ni < 4; ++ni)
            acc[mi][ni] = __builtin_amdgcn_mfma_f32_16x16x32_bf16(afr[mi], bfr[ni], acc[mi][ni], 0, 0, 0);
        __syncthreads();
      }

#pragma unroll
      for (int mi = 0; mi < 4; ++mi) {
#pragma unroll
        for (int ni = 0; ni < 4; ++ni) {
          int col = tn*256 + wc*64 + ni*16 + l15;
          float cv = cvec[col];
#pragma unroll
          for (int reg = 0; reg < 4; ++reg) {
            int row = tm*256 + wr*64 + mi*16 + lk*4 + reg;
            stg_coh(&slotp[(size_t)row*1024 + col], acc[mi][ni][reg] + cv);
          }
        }
      }
      VMCNT0();
      __syncthreads();                       // all waves' stores at LLC
      if (tid == 0) add_rlx(&done[c], 1);
    }
  }
}

// ---------------- host ----------------
extern "C" void kernel_launch(void* const* d_in, const int* in_sizes, int n_in,
                              void* d_out, int out_size, void* d_ws, size_t ws_size,
                              hipStream_t stream) {
  const float* x   = (const float*)d_in[0];
  const float* Wf  = (const float*)d_in[1];
  const float* bf_ = (const float*)d_in[2];
  const float* thf = (const float*)d_in[3];
  const float* Wi  = (const float*)d_in[4];
  const float* bi_ = (const float*)d_in[5];
  const float* thi = (const float*)d_in[6];
  const float* Wg  = (const float*)d_in[7];
  const float* bg_ = (const float*)d_in[8];
  const float* thg = (const float*)d_in[9];
  const float* Wo  = (const float*)d_in[10];
  const float* bo_ = (const float*)d_in[11];
  const float* tho = (const float*)d_in[12];
  float* out = (float*)d_out;

  char* ws = (char*)d_ws;
  unsigned short* Wfull = (unsigned short*)ws;            // 1.5 MB
  float* cvec  = (float*)(ws + 1572864);                  // 4 KB
  int*   flags = (int*)(ws + 1576960);                    // 2 KB (512 ints)
  float* ring  = (float*)(ws + 4194304);                  // RING x 8 MB = 32 MB

  prep_kernel<<<1024, 256, 0, stream>>>(Wf, Wi, Wg, Wo, bf_, bi_, bg_, bo_,
                                        thf, thi, thg, tho, Wfull, cvec, flags);
  persist_kernel<<<NWG, 1024, 0, stream>>>(x, Wfull, cvec, ring,
                                           flags, flags + 128, out);
}

// Round 12
// 3897.689 us; speedup vs baseline: 1.9805x; 1.9805x over previous
//
#include <hip/hip_runtime.h>
#include <hip/hip_bf16.h>
#include <stdint.h>

#define T_STEPS 512
#define BATCH   256
#define HID     256

#define NRC    64      // recurrence WGs: 4 batch rows each, ALL 4 gates, Wh in regs
#define NWWG   192     // xgemm producer WGs
#define NWG    256
#define RING   4       // ring slots
#define CHUNK  8       // time steps per chunk
#define NCHUNK 64
#define TPC    64      // tiles per chunk: (8*256/128) * (1024/256)
#define SLOT_F (CHUNK*256*1024)   // floats per ring slot (8 MB)

using short8 = __attribute__((ext_vector_type(8))) short;
using f32x4  = __attribute__((ext_vector_type(4))) float;

#define VMCNT0() asm volatile("s_waitcnt vmcnt(0)" ::: "memory")

__device__ inline unsigned short f2bf(float f) {
  unsigned u = __float_as_uint(f);
  unsigned r = (u + 0x7fffu + ((u >> 16) & 1u)) >> 16;
  return (unsigned short)r;
}
__device__ inline float sigm(float x)   { return __builtin_amdgcn_rcpf(1.0f + __expf(-x)); }
__device__ inline float tanh_f(float x) { return 2.0f * __builtin_amdgcn_rcpf(1.0f + __expf(-2.0f * x)) - 1.0f; }

__device__ inline int ld_rlx(const int* p) {
  return __hip_atomic_load(p, __ATOMIC_RELAXED, __HIP_MEMORY_SCOPE_AGENT);
}
__device__ inline void add_rlx(int* p, int v) {
  __hip_atomic_fetch_add(p, v, __ATOMIC_RELAXED, __HIP_MEMORY_SCOPE_AGENT);
}
__device__ inline void stg_coh(float* p, float v) {
  __hip_atomic_store(p, v, __ATOMIC_RELAXED, __HIP_MEMORY_SCOPE_AGENT);
}

// h LDS swizzle (proven r4-r7): XOR bits 4..5 with bits 8..9
__device__ inline int hswz(int byte) { return byte ^ (((byte >> 8) & 3) << 4); }

struct RecSm {
  unsigned short hL[4096];      // 8 KB frag-linear h (16 batch cols x 256 k, 4 real)
  float z[4][1032];             // 16.5 KB z (4 rows x 1024 gate-cols + pad)
  float act[4][4][256];         // 16 KB acts [row][gate][col]
  int rdy;
};
struct GemSm { unsigned short aL[4096]; unsigned short bL[8192]; };  // 24 KB

// ---------------- prep: pack weights + zero flags ----------------
// Wfull : [1024 cols][768 k] bf16 (k 0..511 = x part, 512..767 = h part)
__global__ __launch_bounds__(256) void prep_kernel(
    const float* __restrict__ Wf, const float* __restrict__ Wi,
    const float* __restrict__ Wg, const float* __restrict__ Wo,
    const float* __restrict__ bf_, const float* __restrict__ bi_,
    const float* __restrict__ bg_, const float* __restrict__ bo_,
    const float* __restrict__ thf, const float* __restrict__ thi,
    const float* __restrict__ thg, const float* __restrict__ tho,
    unsigned short* __restrict__ Wfull, float* __restrict__ cvec,
    int* __restrict__ flags)
{
  int j = blockIdx.x;            // 0..1023 output col
  int g = j >> 8, col = j & 255;
  const float* W  = (g==0)?Wf:(g==1)?Wi:(g==2)?Wg:Wo;
  const float* bb = (g==0)?bf_:(g==1)?bi_:(g==2)?bg_:bo_;
  const float* th = (g==0)?thf:(g==1)?thi:(g==2)?thg:tho;
  const float* wrow = W + (size_t)col * 768;
  for (int k = threadIdx.x; k < 768; k += blockDim.x)
    Wfull[(size_t)j * 768 + k] = f2bf(wrow[k]);
  if (threadIdx.x == 0) cvec[j] = bb[col] + th[col];
  if (j == 0) for (int i = threadIdx.x; i < 512; i += 256) flags[i] = 0;
}

// ---------------- persistent kernel (512 threads, 8 waves) ----------------
// blocks 0..63   : recurrence, rows bid*4..+3, all 4 gates, Wh register-resident
// blocks 64..255 : xgemm producers filling the Zx ring
__global__ __launch_bounds__(512, 2) void persist_kernel(
    const float* __restrict__ X,
    const unsigned short* __restrict__ Wfull,
    const float* __restrict__ cvec,
    float* __restrict__ ring,
    int* __restrict__ done,       // [64]
    int* __restrict__ consumed,   // [1]
    float* __restrict__ out)
{
  __shared__ union { RecSm rec; GemSm gem; } sm;

  int bid = blockIdx.x, tid = threadIdx.x;
  int lane = tid & 63, wv = tid >> 6;       // 8 waves
  int l15 = lane & 15, lk = lane >> 4;

  if (bid < NRC) {
    // ============ recurrence: Wh in 8x256 VGPRs/lane, no exchange ============
    int bg = bid;
    int cs = wv * 128;                       // this wave's 128 gate-cols (0..1023)
    int sr = wv >> 1;                        // scan row (0..3), 2 waves per row
    int g0 = (wv & 1) * 2;                   // scan gate pair {g0, g0+1}

    for (int i = tid; i < 4096; i += 512) sm.rec.hL[i] = 0;
    if (tid == 0) sm.rec.rdy = 0;

    // one-time Wh preload: 8 col-tiles x 8 k-frags = 256 VGPRs/lane
    short8 af[8][8];
#pragma unroll
    for (int ct = 0; ct < 8; ++ct)
#pragma unroll
      for (int kk = 0; kk < 8; ++kk)
        af[ct][kk] = *(const short8*)(Wfull +
            (size_t)(cs + ct*16 + l15)*768 + 512 + kk*32 + lk*8);

    f32x4 cr = {0.f, 0.f, 0.f, 0.f};         // c-state (waves 0-3): row=wv, col=s*64+lane
    __syncthreads();

    for (int t = 0; t < T_STEPS; ++t) {
      int cIdx = t >> 3;

      // ---- chunk gate (LDS-speculated; poll only if not already done) ----
      if ((t & 7) == 0) {
        if (sm.rec.rdy < TPC) {
          if (tid == 0) { while (ld_rlx(&done[cIdx]) < TPC) __builtin_amdgcn_s_sleep(1); }
          __syncthreads();
        }
      }

      // ---- issue 8 zx loads (LLC, pipelined, waited before scan) ----
      const float* zb = ring + (size_t)(cIdx & (RING-1))*SLOT_F
                      + ((size_t)(t & 7)*256 + bg*4 + sr)*1024 + g0*256 + lane;
      float z0,z1,z2,z3,z4,z5,z6,z7;
      asm volatile(
        "global_load_dword %0, %8, off sc0 sc1\n\t"
        "global_load_dword %1, %8, off offset:256 sc0 sc1\n\t"
        "global_load_dword %2, %8, off offset:512 sc0 sc1\n\t"
        "global_load_dword %3, %8, off offset:768 sc0 sc1\n\t"
        "global_load_dword %4, %8, off offset:1024 sc0 sc1\n\t"
        "global_load_dword %5, %8, off offset:1280 sc0 sc1\n\t"
        "global_load_dword %6, %8, off offset:1536 sc0 sc1\n\t"
        "global_load_dword %7, %8, off offset:1792 sc0 sc1"
        : "=&v"(z0), "=&v"(z1), "=&v"(z2), "=&v"(z3),
          "=&v"(z4), "=&v"(z5), "=&v"(z6), "=&v"(z7)
        : "v"(zb)
        : "memory");

      // ---- MFMA: z = Wh(regs) x h(LDS), 8 col-tiles x K=256 ----
      short8 hb[8];
#pragma unroll
      for (int kk = 0; kk < 8; ++kk)
        hb[kk] = *(const short8*)((const char*)sm.rec.hL + hswz(kk*1024 + lane*16));
      f32x4 acc[8];
#pragma unroll
      for (int ct = 0; ct < 8; ++ct) acc[ct] = (f32x4){0.f,0.f,0.f,0.f};
#pragma unroll
      for (int kk = 0; kk < 8; ++kk)
#pragma unroll
        for (int ct = 0; ct < 8; ++ct)
          acc[ct] = __builtin_amdgcn_mfma_f32_16x16x32_bf16(af[ct][kk], hb[kk], acc[ct], 0, 0, 0);
      if (l15 < 4) {   // D: col(batch)=l15, row(gate-col)=lk*4+reg
#pragma unroll
        for (int ct = 0; ct < 8; ++ct)
          *(f32x4*)&sm.rec.z[l15][cs + ct*16 + lk*4] = acc[ct];
      }
      __syncthreads();

      // ---- scan: wave handles (row sr, gates g0,g0+1); 8 interleaved segs ----
      asm volatile("s_waitcnt vmcnt(0)" ::: "memory");
      __builtin_amdgcn_sched_barrier(0);
      float v[8];
      v[0] = __cosf(sm.rec.z[sr][g0*256       + lane] + z0);
      v[1] = __cosf(sm.rec.z[sr][g0*256 +  64 + lane] + z1);
      v[2] = __cosf(sm.rec.z[sr][g0*256 + 128 + lane] + z2);
      v[3] = __cosf(sm.rec.z[sr][g0*256 + 192 + lane] + z3);
      v[4] = __cosf(sm.rec.z[sr][g0*256 + 256 + lane] + z4);
      v[5] = __cosf(sm.rec.z[sr][g0*256 + 320 + lane] + z5);
      v[6] = __cosf(sm.rec.z[sr][g0*256 + 384 + lane] + z6);
      v[7] = __cosf(sm.rec.z[sr][g0*256 + 448 + lane] + z7);
#pragma unroll
      for (int off = 1; off < 64; off <<= 1) {
        float u[8];
#pragma unroll
        for (int k = 0; k < 8; ++k) u[k] = __shfl_up(v[k], (unsigned)off, 64);
        if (lane >= off) {
#pragma unroll
          for (int k = 0; k < 8; ++k) v[k] *= u[k];
        }
      }
      float tA0 = __shfl(v[0], 63, 64), tA1 = __shfl(v[1], 63, 64), tA2 = __shfl(v[2], 63, 64);
      float tB0 = __shfl(v[4], 63, 64), tB1 = __shfl(v[5], 63, 64), tB2 = __shfl(v[6], 63, 64);
      float pA2 = tA0*tA1, pA3 = pA2*tA2;
      float pB2 = tB0*tB1, pB3 = pB2*tB2;
      float aA[4] = {v[0], v[1]*tA0, v[2]*pA2, v[3]*pA3};
      float aB[4] = {v[4], v[5]*tB0, v[6]*pB2, v[7]*pB3};
      // gates: g0, g0+1.  g==2 -> tanh, else sigmoid
      if (g0 == 0) {
#pragma unroll
        for (int s = 0; s < 4; ++s) { aA[s] = sigm(aA[s]); aB[s] = sigm(aB[s]); }
      } else {
#pragma unroll
        for (int s = 0; s < 4; ++s) { aA[s] = tanh_f(aA[s]); aB[s] = sigm(aB[s]); }
      }
#pragma unroll
      for (int s = 0; s < 4; ++s) {
        sm.rec.act[sr][g0    ][s*64 + lane] = aA[s];
        sm.rec.act[sr][g0 + 1][s*64 + lane] = aB[s];
      }
      __syncthreads();

      // ---- update (waves 0-3: row = wv) ----
      if (wv < 4) {
        int brow = bg*4 + wv;
#pragma unroll
        for (int s = 0; s < 4; ++s) {
          int k = s*64 + lane;
          float fv = sm.rec.act[wv][0][k];
          float iv = sm.rec.act[wv][1][k];
          float gv = sm.rec.act[wv][2][k];
          float ov = sm.rec.act[wv][3][k];
          float cn = fv*cr[s] + iv*gv;
          cr[s] = cn;
          float h = ov*tanh_f(cn);
          int byte = (k >> 5)*1024 + ((k >> 3) & 3)*256 + wv*16 + (k & 7)*2;
          *(unsigned short*)((char*)sm.rec.hL + hswz(byte)) = f2bf(h);
          out[(size_t)t*(BATCH*HID) + (size_t)brow*256 + k] = h;
          if (t == T_STEPS-1) {
            out[(size_t)T_STEPS*(BATCH*HID) + (size_t)brow*256 + k] = h;
            out[(size_t)T_STEPS*(BATCH*HID) + BATCH*HID + (size_t)brow*256 + k] = cn;
          }
        }
      }

      // ---- speculation + consumed ----
      if ((t & 7) == 6 && tid == 0) sm.rec.rdy = ld_rlx(&done[cIdx + 1]);
      if ((t & 7) == 7 && tid == 0) add_rlx(consumed, 1);
      __syncthreads();   // hL(t) complete; act/z reads done
    }
  } else {
    // ============ xgemm producers (proven r5 code; 128x256 tiles) ============
    int w0 = bid - NRC;
    int wr = wv >> 2, wc = wv & 3;          // 2 x 4 wave grid, 64x64 per wave
    int rA = tid >> 2, kA = (tid & 3) * 8;  // A staging: 128 rows x 32 k
    int rB = tid >> 1, kB = (tid & 1) * 16; // B staging: 256 cols x 32 k

    for (int gt = w0; gt < NCHUNK * TPC; gt += NWWG) {
      int c  = gt >> 6;
      int tl = gt & 63;
      int tm = tl >> 2, tn = tl & 3;

      int need = NRC * (c - RING + 1);
      if (need > 0) {
        if (tid == 0) { while (ld_rlx(consumed) < need) __builtin_amdgcn_s_sleep(8); }
        __syncthreads();
      }

      const float* Xb = X + ((size_t)c*(CHUNK*256) + (size_t)tm*128) * 512;
      float* slotp = ring + (size_t)(c & (RING-1)) * SLOT_F;

      f32x4 acc[4][4];
#pragma unroll
      for (int mi = 0; mi < 4; ++mi)
#pragma unroll
        for (int ni = 0; ni < 4; ++ni) acc[mi][ni] = (f32x4){0.f,0.f,0.f,0.f};

      int slotA = (rA >> 4)*1024 + ((tid & 3)*16 + (rA & 15))*16;
      int baseB = (rB >> 4)*1024;
      int kO = kB >> 3;
      int slotB0 = baseB + ((kO    )*16 + (rB & 15))*16;
      int slotB1 = baseB + ((kO + 1)*16 + (rB & 15))*16;

      for (int kb = 0; kb < 512; kb += 32) {
        const float* ap = Xb + (size_t)rA*512 + kb + kA;
        f32x4 v0 = *(const f32x4*)ap;
        f32x4 v1 = *(const f32x4*)(ap + 4);
        unsigned short t8[8];
        t8[0]=f2bf(v0[0]); t8[1]=f2bf(v0[1]); t8[2]=f2bf(v0[2]); t8[3]=f2bf(v0[3]);
        t8[4]=f2bf(v1[0]); t8[5]=f2bf(v1[1]); t8[6]=f2bf(v1[2]); t8[7]=f2bf(v1[3]);
        *(short8*)((char*)sm.gem.aL + slotA) = *(short8*)t8;
        const unsigned short* bp = Wfull + (size_t)(tn*256 + rB)*768 + kb + kB;
        *(short8*)((char*)sm.gem.bL + slotB0) = *(const short8*)bp;
        *(short8*)((char*)sm.gem.bL + slotB1) = *(const short8*)(bp + 8);
        __syncthreads();

        short8 afr[4], bfr4[4];
#pragma unroll
        for (int mi = 0; mi < 4; ++mi)
          afr[mi]  = *(const short8*)((const char*)sm.gem.aL + (wr*4 + mi)*1024 + lane*16);
#pragma unroll
        for (int ni = 0; ni < 4; ++ni)
          bfr4[ni] = *(const short8*)((const char*)sm.gem.bL + (wc*4 + ni)*1024 + lane*16);
#pragma unroll
        for (int mi = 0; mi < 4; ++mi)
#pragma unroll
          for (int ni = 0; ni < 4; ++ni)
            acc[mi][ni] = __builtin_amdgcn_mfma_f32_16x16x32_bf16(afr[mi], bfr4[ni], acc[mi][ni], 0, 0, 0);
        __syncthreads();
      }

#pragma unroll
      for (int mi = 0; mi < 4; ++mi) {
#pragma unroll
        for (int ni = 0; ni < 4; ++ni) {
          int col = tn*256 + wc*64 + ni*16 + l15;
          float cv = cvec[col];
#pragma unroll
          for (int reg = 0; reg < 4; ++reg) {
            int row = tm*128 + wr*64 + mi*16 + lk*4 + reg;
            stg_coh(&slotp[(size_t)row*1024 + col], acc[mi][ni][reg] + cv);
          }
        }
      }
      VMCNT0();
      __syncthreads();                       // all waves' stores at LLC
      if (tid == 0) add_rlx(&done[c], 1);
    }
  }
}

// ---------------- host ----------------
extern "C" void kernel_launch(void* const* d_in, const int* in_sizes, int n_in,
                              void* d_out, int out_size, void* d_ws, size_t ws_size,
                              hipStream_t stream) {
  const float* x   = (const float*)d_in[0];
  const float* Wf  = (const float*)d_in[1];
  const float* bf_ = (const float*)d_in[2];
  const float* thf = (const float*)d_in[3];
  const float* Wi  = (const float*)d_in[4];
  const float* bi_ = (const float*)d_in[5];
  const float* thi = (const float*)d_in[6];
  const float* Wg  = (const float*)d_in[7];
  const float* bg_ = (const float*)d_in[8];
  const float* thg = (const float*)d_in[9];
  const float* Wo  = (const float*)d_in[10];
  const float* bo_ = (const float*)d_in[11];
  const float* tho = (const float*)d_in[12];
  float* out = (float*)d_out;

  char* ws = (char*)d_ws;
  unsigned short* Wfull = (unsigned short*)ws;            // 1.5 MB
  float* cvec  = (float*)(ws + 1572864);                  // 4 KB
  int*   flags = (int*)(ws + 1576960);                    // 2 KB (512 ints)
  float* ring  = (float*)(ws + 4194304);                  // RING x 8 MB = 32 MB

  prep_kernel<<<1024, 256, 0, stream>>>(Wf, Wi, Wg, Wo, bf_, bi_, bg_, bo_,
                                        thf, thi, thg, tho, Wfull, cvec, flags);
  persist_kernel<<<NWG, 512, 0, stream>>>(x, Wfull, cvec, ring,
                                          flags, flags + 128, out);
}